// Round 9
// baseline (290.468 us; speedup 1.0000x reference)
//
#include <hip/hip_runtime.h>

// DigitCaps dynamic routing, MI355X — round 9: fully-fused routed passes.
// vs r8 (280us): D-sweep + softmax + S-sweep merged into ONE kernel per pass
// (u recomputed from in-register frags: 8 extra MFMA instead of 64MB d/c
// round-trips + extra Wt sweep). 3 sweeps total (was 5), no softmax/
// squash_reduce kernels, atomicAdd outputs (no 32MB s_part).
//
// u_hat[b,j,i,p] = sum_q x[b,i,q] W[j,i,p,q];  b=64, i=2048, j=32, p=32, q=16
// Pass A: s1 = (1/32) sum_i u_hat ; v1 = squash(s1)
// Pass B: per i: d=sum_p v1*u_hat ; c=softmax_j d ; s2 += c*u_hat ; v2=squash
// Pass C: v = v1+v2 (logits linear in v) ; out = squash(s3)
//
// Block: 1024 thr = 16 waves = 32 b x ALL 32 j (wave: 2 j x 2 bg), TI=16 i.
// Grid: 256 = 2 b-halves x 128 i-tiles -> 1 block/CU, 4 waves/SIMD.
// XCD swizzle: consecutive V = same i-tile's 2 b-halves -> share Wt[i] in L2.
//
// MFMA 16x16x32 bf16: A k0-15 = hi(x), k16-31 = lo residual; B k-halves
// replicate W => A-side fp32-exact, only W rounded once. v packed bf16x2 for
// the logit dot only (softmax weights perturbed ~0.3%, under threshold).

namespace {

using bfrag = __attribute__((ext_vector_type(8))) short;   // 8 bf16 = 4 VGPR
using ffrag = __attribute__((ext_vector_type(4))) float;   // 4 fp32

constexpr int I_DIM = 2048;
constexpr int B_DIM = 64;
constexpr int N_DIM = 1024;
constexpr int TI    = 16;

__device__ __forceinline__ unsigned short f2bf(float f) {
    unsigned int u = __float_as_uint(f);
    return (unsigned short)((u + 0x7fffu + ((u >> 16) & 1u)) >> 16);
}
__device__ __forceinline__ float bflo(unsigned int u) {
    return __uint_as_float(u << 16);
}
__device__ __forceinline__ float bfhi(unsigned int u) {
    return __uint_as_float(u & 0xffff0000u);
}

template<int CTRL>
__device__ __forceinline__ float dppf(float x) {
    return __int_as_float(
        __builtin_amdgcn_update_dpp(0, __float_as_int(x), CTRL, 0xF, 0xF, true));
}
__device__ __forceinline__ float sum16(float x) {
    x += dppf<0x121>(x); x += dppf<0x122>(x);
    x += dppf<0x124>(x); x += dppf<0x128>(x);
    return x;
}
__device__ __forceinline__ float max16(float x) {
    x = fmaxf(x, dppf<0x121>(x)); x = fmaxf(x, dppf<0x122>(x));
    x = fmaxf(x, dppf<0x124>(x)); x = fmaxf(x, dppf<0x128>(x));
    return x;
}

__device__ __forceinline__ void barrier_lgkm() {
    asm volatile("s_waitcnt lgkmcnt(0)" ::: "memory");
    __builtin_amdgcn_s_barrier();
    __builtin_amdgcn_sched_barrier(0);
}

// ---------------- conversion kernels (r8-proven layouts) ----------------

// Wt[i][h][n][8] <- W[j][i][p][q] fp32  (n = j*32+p, h = q-half)
__global__ __launch_bounds__(256)
void conv_w(const float* __restrict__ W, unsigned short* __restrict__ Wt) {
    const int t = blockIdx.x * 256 + threadIdx.x;          // (i,n)
    const int i = t >> 10, n = t & 1023;
    const float* src = W + ((((n >> 5) * I_DIM + i) * 32 + (n & 31)) << 4);
    unsigned int o[8];
    #pragma unroll
    for (int k = 0; k < 8; ++k)
        o[k] = (unsigned int)f2bf(src[2 * k]) | ((unsigned int)f2bf(src[2 * k + 1]) << 16);
    uint4* d0 = reinterpret_cast<uint4*>(Wt + (((size_t)i * 2 + 0) * 1024 + n) * 8);
    uint4* d1 = reinterpret_cast<uint4*>(Wt + (((size_t)i * 2 + 1) * 1024 + n) * 8);
    *d0 = make_uint4(o[0], o[1], o[2], o[3]);
    *d1 = make_uint4(o[4], o[5], o[6], o[7]);
}

// xT2[i][g][b][8] <- x[b][i][q] fp32  (g0/1 = hi q0-7/q8-15, g2/3 = lo residual)
__global__ __launch_bounds__(256)
void conv_x(const float* __restrict__ x, unsigned short* __restrict__ xT2) {
    const int t = blockIdx.x * 256 + threadIdx.x;          // (i,b)
    const int i = t >> 6, b = t & 63;
    const float* src = x + (((size_t)b * I_DIM + i) << 4);
    unsigned int o[16];
    #pragma unroll
    for (int k = 0; k < 8; ++k) {
        const float f0 = src[2 * k], f1 = src[2 * k + 1];
        const unsigned short h0 = f2bf(f0), h1 = f2bf(f1);
        const float l0 = f0 - __uint_as_float(((unsigned int)h0) << 16);
        const float l1 = f1 - __uint_as_float(((unsigned int)h1) << 16);
        o[k]     = (unsigned int)h0       | ((unsigned int)h1 << 16);
        o[8 + k] = (unsigned int)f2bf(l0) | ((unsigned int)f2bf(l1) << 16);
    }
    #pragma unroll
    for (int g = 0; g < 4; ++g) {
        uint4* dst = reinterpret_cast<uint4*>(xT2 + (((size_t)i * 4 + g) * 64 + b) * 8);
        *dst = make_uint4(o[4 * g], o[4 * g + 1], o[4 * g + 2], o[4 * g + 3]);
    }
}

// ---------------- fused routing pass ----------------
template<int ROUTED>
__global__ __launch_bounds__(1024, 4)
void caps_pass2(const unsigned short* __restrict__ Wt,   // [I][2][1024][8]
                const unsigned short* __restrict__ xT2,  // [I][4][64][8]
                const float* __restrict__ v_in,          // [64][32][32] (ROUTED)
                float* __restrict__ s_out)               // [64][1024]
{
    __shared__ float d_buf[32 * 34];
    __shared__ float c_buf[32 * 34];

    const int tid = threadIdx.x;
    const int w   = tid >> 6;          // wave 0..15
    const int l   = tid & 63;
    const int g   = l >> 4;            // 16-lane group (k-chunk)
    const int li  = l & 15;
    const int j0  = w << 1;            // 2 j per wave

    // XCD swizzle: V = 2*it + bh; the 2 b-halves of an i-tile are consecutive
    // on one XCD -> second block's Wt[i] reads hit that XCD's L2.
    const int bid = (int)blockIdx.x;
    const int V   = ((bid & 7) << 5) | (bid >> 3);
    const int it  = V >> 1;
    const int bh  = V & 1;
    const int b0  = bh << 5;
    const int i0  = it << 4;

    // frag offsets (shorts): A at aoff + bg*128; B at boff + jj*256 + ph*128
    const int aoff = (g << 9) + ((b0 + li) << 3);
    const int boff = ((g & 1) << 13) + (j0 << 8) + (li << 3);

    // v packed bf16x2 (ph0, ph1) — logit dot only
    unsigned int vr[2][4][2];
    if (ROUTED) {
        #pragma unroll
        for (int bg = 0; bg < 2; ++bg)
            #pragma unroll
            for (int r = 0; r < 4; ++r)
                #pragma unroll
                for (int jj = 0; jj < 2; ++jj) {
                    const int b = b0 + (bg << 4) + (g << 2) + r;
                    const float* vp = v_in + (((b << 5) + j0 + jj) << 5);
                    vr[bg][r][jj] = (unsigned int)f2bf(vp[li])
                                  | ((unsigned int)f2bf(vp[li + 16]) << 16);
                }
    }

    ffrag s[2][4];
    #pragma unroll
    for (int bg = 0; bg < 2; ++bg)
        #pragma unroll
        for (int t = 0; t < 4; ++t) s[bg][t] = ffrag{0.f, 0.f, 0.f, 0.f};

    for (int ii = 0; ii < TI; ++ii) {
        const int i = i0 + ii;
        const unsigned short* xa = xT2 + ((size_t)i << 11) + aoff;
        const unsigned short* xb = Wt + ((size_t)i << 14) + boff;
        const bfrag A0 = *reinterpret_cast<const bfrag*>(xa);
        const bfrag A1 = *reinterpret_cast<const bfrag*>(xa + 128);
        bfrag Bf[4];
        #pragma unroll
        for (int t = 0; t < 4; ++t)
            Bf[t] = *reinterpret_cast<const bfrag*>(xb + ((t >> 1) << 8) + ((t & 1) << 7));

        if constexpr (!ROUTED) {
            #pragma unroll
            for (int t = 0; t < 4; ++t) {
                s[0][t] = __builtin_amdgcn_mfma_f32_16x16x32_bf16(A0, Bf[t], s[0][t], 0, 0, 0);
                s[1][t] = __builtin_amdgcn_mfma_f32_16x16x32_bf16(A1, Bf[t], s[1][t], 0, 0, 0);
            }
        } else {
            const ffrag z{0.f, 0.f, 0.f, 0.f};
            // ---- round 1: logits d[b,j] = sum_p v*u ----
            #pragma unroll
            for (int bg = 0; bg < 2; ++bg) {
                const bfrag a = bg ? A1 : A0;
                const ffrag u0 = __builtin_amdgcn_mfma_f32_16x16x32_bf16(a, Bf[0], z, 0, 0, 0);
                const ffrag u1 = __builtin_amdgcn_mfma_f32_16x16x32_bf16(a, Bf[1], z, 0, 0, 0);
                const ffrag u2 = __builtin_amdgcn_mfma_f32_16x16x32_bf16(a, Bf[2], z, 0, 0, 0);
                const ffrag u3 = __builtin_amdgcn_mfma_f32_16x16x32_bf16(a, Bf[3], z, 0, 0, 0);
                #pragma unroll
                for (int r = 0; r < 4; ++r) {
                    const unsigned int v0 = vr[bg][r][0], v1 = vr[bg][r][1];
                    float d0 = u0[r] * bflo(v0) + u1[r] * bfhi(v0);
                    float d1 = u2[r] * bflo(v1) + u3[r] * bfhi(v1);
                    d0 = sum16(d0);
                    d1 = sum16(d1);
                    const float dsel = (li & 1) ? d1 : d0;
                    if (li < 2)
                        d_buf[((bg << 4) + (g << 2) + r) * 34 + j0 + li] = dsel;
                }
            }
            barrier_lgkm();   // d_buf complete

            // ---- softmax over j: 32 b-rows x 32 j = all 1024 threads ----
            {
                const int bl = tid >> 5, jx = tid & 31;
                const float dv = d_buf[bl * 34 + jx];
                float m = max16(dv);
                m = fmaxf(m, __shfl_xor(m, 16));
                const float e = __expf(dv - m);
                float sm = sum16(e);
                sm += __shfl_xor(sm, 16);
                c_buf[bl * 34 + jx] = e / sm;
            }
            barrier_lgkm();   // c_buf complete (also fences last iter's c reads)

            // ---- round 2: s += c * u (recompute u from in-register frags) ----
            #pragma unroll
            for (int bg = 0; bg < 2; ++bg) {
                const bfrag a = bg ? A1 : A0;
                float2 c2[4];
                #pragma unroll
                for (int r = 0; r < 4; ++r)
                    c2[r] = *reinterpret_cast<const float2*>(
                        &c_buf[((bg << 4) + (g << 2) + r) * 34 + j0]);
                #pragma unroll
                for (int t = 0; t < 4; ++t) {
                    const ffrag u = __builtin_amdgcn_mfma_f32_16x16x32_bf16(a, Bf[t], z, 0, 0, 0);
                    #pragma unroll
                    for (int r = 0; r < 4; ++r)
                        s[bg][t][r] += ((t >> 1) ? c2[r].y : c2[r].x) * u[r];
                }
            }
        }
    }

    const float sc = ROUTED ? 1.f : (1.f / 32.f);
    #pragma unroll
    for (int bg = 0; bg < 2; ++bg)
        #pragma unroll
        for (int t = 0; t < 4; ++t)
            #pragma unroll
            for (int r = 0; r < 4; ++r)
                atomicAdd(&s_out[(size_t)(b0 + (bg << 4) + (g << 2) + r) * N_DIM
                                 + ((j0 + (t >> 1)) << 5) + ((t & 1) << 4) + li],
                          s[bg][t][r] * sc);
}

// dst[row] = (base ? base[row] : 0) + squash(s[row]),  row = (b,j)
__global__ __launch_bounds__(256)
void squash_add(const float* __restrict__ s, const float* __restrict__ base,
                float* __restrict__ dst) {
    const int t = blockIdx.x * 256 + threadIdx.x;
    if (t >= B_DIM * 32) return;
    const float* sp = s + t * 32;
    float n2 = 0.f;
    #pragma unroll
    for (int p = 0; p < 32; ++p) { const float xv = sp[p]; n2 += xv * xv; }
    const float scl = n2 / ((1.f + n2) * sqrtf(n2 + 1e-7f));
    float* op = dst + t * 32;
    #pragma unroll
    for (int p = 0; p < 32; ++p)
        op[p] = (base ? base[t * 32 + p] : 0.f) + scl * sp[p];
}

} // namespace

extern "C" void kernel_launch(void* const* d_in, const int* in_sizes, int n_in,
                              void* d_out, int out_size, void* d_ws, size_t ws_size,
                              hipStream_t stream) {
    const float* x = (const float*)d_in[0];   // [64, 2048, 16]
    const float* W = (const float*)d_in[1];   // [32, 2048, 32, 16]
    float* out = (float*)d_out;               // [64, 32, 32]

    const size_t needW = (size_t)I_DIM * 2 * 1024 * 8 * 2;   // 64 MB bf16 Wt
    const size_t needX = (size_t)I_DIM * 4 * 64 * 8 * 2;     //  8 MB bf16 xT2
    const size_t needS = (size_t)B_DIM * N_DIM * 4;          // 256 KB

    char* pp = (char*)d_ws;
    unsigned short* Wt  = (unsigned short*)pp; pp += needW;
    unsigned short* xT2 = (unsigned short*)pp; pp += needX;
    float* s  = (float*)pp; pp += needS;
    float* v1 = (float*)pp; pp += needS;
    float* vs = (float*)pp;
    (void)ws_size;

    conv_x<<<(I_DIM * B_DIM) / 256, 256, 0, stream>>>(x, xT2);
    conv_w<<<(I_DIM * N_DIM) / 256, 256, 0, stream>>>(W, Wt);

    const dim3 rg(256), rb(1024);

    // pass A: uniform c = 1/32
    hipMemsetAsync(s, 0, needS, stream);
    caps_pass2<0><<<rg, rb, 0, stream>>>(Wt, xT2, nullptr, s);
    squash_add<<<8, 256, 0, stream>>>(s, nullptr, v1);

    // pass B: v = v1
    hipMemsetAsync(s, 0, needS, stream);
    caps_pass2<1><<<rg, rb, 0, stream>>>(Wt, xT2, v1, s);
    squash_add<<<8, 256, 0, stream>>>(s, v1, vs);           // vs = v1 + v2

    // pass C: v = v1+v2 (logits linear in v)
    hipMemsetAsync(s, 0, needS, stream);
    caps_pass2<1><<<rg, rb, 0, stream>>>(Wt, xT2, vs, s);
    squash_add<<<8, 256, 0, stream>>>(s, nullptr, out);
}